// Round 3
// baseline (285.870 us; speedup 1.0000x reference)
//
#include <hip/hip_runtime.h>

typedef short short8 __attribute__((ext_vector_type(8)));
typedef float floatx4 __attribute__((ext_vector_type(4)));

#define C_DIM 512
#define KQ_STRIDE 1040   // bytes per row of the LDS k/p tile (512*2 + 16 pad)
#define ROWS 32          // rows per block

__device__ __forceinline__ unsigned short f2bf(float f) {
    unsigned u = __builtin_bit_cast(unsigned, f);
    u = u + 0x7fffu + ((u >> 16) & 1u);
    return (unsigned short)(u >> 16);
}

// Monotone uint key for argmax: order-preserving encoding of float s, with the
// 9 low bits replaced by (511-col) so uint-max == (max s, then min col) to the
// granularity of 9 truncated mantissa bits (~2.4e-4 on m; only feeds scalars).
__device__ __forceinline__ unsigned skey(float s, int col) {
    unsigned u = __builtin_bit_cast(unsigned, s);
    u = ((int)u < 0) ? ~u : (u | 0x80000000u);
    return (u & ~0x1FFu) | (unsigned)(511 - col);
}

// ---------------- pack kernel: keys -> B-frag order (score GEMM), values -> B-frag
// order (PV GEMM), plus passthrough copies of keys/values and scal zeroing.
// B fragment for mfma_f32_16x16x32_bf16: lane l holds B[k=(l>>4)*8+j][n=l&15], j=0..7
__global__ __launch_bounds__(256) void pack_kernel(
    const float* __restrict__ keys, const float* __restrict__ values,
    unsigned short* __restrict__ keysFrag, unsigned short* __restrict__ valsFrag,
    float* __restrict__ keysOut, float* __restrict__ valsOut,
    float* __restrict__ scal) {
    int tid = blockIdx.x * 256 + threadIdx.x;
    if (tid < 65536) {
        int e  = tid & 32767;
        int l  = e & 63;
        int NT = (e >> 6) & 31;
        int kt = e >> 11;                           // 0..15
        int li = l & 15, q4 = l >> 4;
        unsigned short tmp[8];
        if (tid < 32768) {
            // score GEMM: B[k][n] = keys[n][k], keys is [M, C] row-major
            const float* s = keys + (size_t)(NT * 16 + li) * C_DIM + kt * 32 + q4 * 8;
#pragma unroll
            for (int j = 0; j < 8; j++) tmp[j] = f2bf(s[j]);
            unsigned short* d = keysFrag + ((size_t)(kt * 32 + NT) * 64 + l) * 8;
            *(ushort4*)d       = make_ushort4(tmp[0], tmp[1], tmp[2], tmp[3]);
            *(ushort4*)(d + 4) = make_ushort4(tmp[4], tmp[5], tmp[6], tmp[7]);
        } else {
            // PV GEMM: B[k][n] = values[k][n], k indexes M
#pragma unroll
            for (int j = 0; j < 8; j++)
                tmp[j] = f2bf(values[(size_t)(kt * 32 + q4 * 8 + j) * C_DIM + NT * 16 + li]);
            unsigned short* d = valsFrag + ((size_t)(kt * 32 + NT) * 64 + l) * 8;
            *(ushort4*)d       = make_ushort4(tmp[0], tmp[1], tmp[2], tmp[3]);
            *(ushort4*)(d + 4) = make_ushort4(tmp[4], tmp[5], tmp[6], tmp[7]);
        }
    } else {
        int ct = tid - 65536;                       // 0..32767
        if (ct == 0) { scal[0] = 0.f; scal[1] = 0.f; scal[2] = 0.f; }
#pragma unroll
        for (int i = 0; i < 4; i++) {
            int idx = ct + i * 32768;               // 0..131071 float4s
            if (idx < 65536) ((float4*)keysOut)[idx] = ((const float4*)keys)[idx];
            else             ((float4*)valsOut)[idx - 65536] = ((const float4*)values)[idx - 65536];
        }
    }
}

// ---------------- fused main kernel: 32 rows per block, 512 threads (8 waves)
// 32-row tile: LDS 37.4 KB -> up to 4 blocks/CU (was 2 at 64 rows). Shiftless
// softmax; branch-free stats butterflies; redundant per-wave cross-wave merge;
// coalesced float4 output stores via wave-private LDS bounce (fixes the 2.08x
// WRITE_SIZE amplification from 4B/lane scattered stores).
__global__ __launch_bounds__(512, 6) void fused_kernel(
    const float* __restrict__ key,
    const float* __restrict__ query,
    const unsigned short* __restrict__ keysFrag,
    const unsigned short* __restrict__ valsFrag,
    const float* __restrict__ values,
    float* __restrict__ outRQ,
    float* __restrict__ scal) {   // [0]=entropy, [1]=gather, [2]=contrast
    __shared__ char kq[ROWS * KQ_STRIDE];            // k bf16 tile -> p tile -> f32 store-stage
    __shared__ __align__(16) float stats[8][ROWS][4];// [wave][row][key,z1,e1,z2]
    __shared__ float gpart[8];

    const int tid = threadIdx.x;
    const int w  = tid >> 6;
    const int l  = tid & 63;
    const int li = l & 15;
    const int q4 = l >> 4;
    const int row0 = blockIdx.x << 5;

    // ---- phase 0: load 4 rows/wave, l2-normalize, write bf16 to LDS ----
    {
        int r = (w << 2) + q4;                       // 16 lanes per row
        const float4* src = (const float4*)(key + (size_t)(row0 + r) * C_DIM);
        float4 v[8];
        float ss = 0.f;
#pragma unroll
        for (int i = 0; i < 8; i++) {
            v[i] = src[i * 16 + li];
            ss += v[i].x * v[i].x + v[i].y * v[i].y + v[i].z * v[i].z + v[i].w * v[i].w;
        }
#pragma unroll
        for (int m = 1; m < 16; m <<= 1) ss += __shfl_xor(ss, m, 64);
        float inv = 1.0f / fmaxf(sqrtf(ss), 1e-12f);
        char* dstrow = kq + r * KQ_STRIDE;
#pragma unroll
        for (int i = 0; i < 8; i++) {
            ushort4 b = make_ushort4(f2bf(v[i].x * inv), f2bf(v[i].y * inv),
                                     f2bf(v[i].z * inv), f2bf(v[i].w * inv));
            *(ushort4*)(dstrow + i * 128 + li * 8) = b;
        }
    }
    __syncthreads();

    // ---- phase 1: score GEMM, 32 rows x cols [w*64, +64), B prefetched one kt ahead ----
    floatx4 acc1[8];                         // [rg*4+nt], rg in {0,1}
#pragma unroll
    for (int i = 0; i < 8; i++) acc1[i] = (floatx4){0.f, 0.f, 0.f, 0.f};
    {
        const short8* kf = (const short8*)keysFrag;
        short8 bcur[4], bnxt[4];
#pragma unroll
        for (int nt = 0; nt < 4; nt++) bcur[nt] = kf[(size_t)((w * 4 + nt) * 64 + l)];
        for (int kt = 0; kt < 16; kt++) {
            if (kt < 15) {
#pragma unroll
                for (int nt = 0; nt < 4; nt++)
                    bnxt[nt] = kf[(size_t)(((kt + 1) * 32 + w * 4 + nt) * 64 + l)];
            }
            short8 a[2];
#pragma unroll
            for (int rg = 0; rg < 2; rg++)
                a[rg] = *(const short8*)(kq + (rg * 16 + li) * KQ_STRIDE + kt * 64 + q4 * 16);
#pragma unroll
            for (int rg = 0; rg < 2; rg++)
#pragma unroll
                for (int nt = 0; nt < 4; nt++)
                    acc1[rg * 4 + nt] = __builtin_amdgcn_mfma_f32_16x16x32_bf16(
                        a[rg], bcur[nt], acc1[rg * 4 + nt], 0, 0, 0);
#pragma unroll
            for (int nt = 0; nt < 4; nt++) bcur[nt] = bnxt[nt];
        }
    }

    // ---- phase 2: per-row partial stats (shiftless), overwrite acc1 with p ----
    // C layout: col = li, row = q4*4 + reg.
#pragma unroll
    for (int rg = 0; rg < 2; rg++) {
#pragma unroll
        for (int reg = 0; reg < 4; reg++) {
            const int colbase = (w << 6) + li;
            float s0 = acc1[rg * 4 + 0][reg];
            float s1 = acc1[rg * 4 + 1][reg];
            float s2 = acc1[rg * 4 + 2][reg];
            float s3 = acc1[rg * 4 + 3][reg];
            unsigned K  = skey(s0, colbase);
            unsigned K1 = skey(s1, colbase + 16);
            unsigned K2 = skey(s2, colbase + 32);
            unsigned K3 = skey(s3, colbase + 48);
            K = K1 > K ? K1 : K;
            K = K2 > K ? K2 : K;
            K = K3 > K ? K3 : K;
            float p0 = __expf(s0), p1 = __expf(s1), p2 = __expf(s2), p3 = __expf(s3);
            float z1 = (p0 + p1) + (p2 + p3);
            float e1 = p0 * s0 + p1 * s1 + p2 * s2 + p3 * s3;
            float z2 = p0 * p0 + p1 * p1 + p2 * p2 + p3 * p3;
            acc1[rg * 4 + 0][reg] = p0;
            acc1[rg * 4 + 1][reg] = p1;
            acc1[rg * 4 + 2][reg] = p2;
            acc1[rg * 4 + 3][reg] = p3;
#pragma unroll
            for (int msk = 1; msk < 16; msk <<= 1) {
                unsigned Ko = __shfl_xor(K, msk, 64);
                z1 += __shfl_xor(z1, msk, 64);
                e1 += __shfl_xor(e1, msk, 64);
                z2 += __shfl_xor(z2, msk, 64);
                K = Ko > K ? Ko : K;
            }
            if (li == 0) {
                floatx4 sv;
                sv[0] = __builtin_bit_cast(float, K);
                sv[1] = z1; sv[2] = e1; sv[3] = z2;
                *(floatx4*)stats[w][rg * 16 + q4 * 4 + reg] = sv;
            }
        }
    }
    __syncthreads();

    // ---- phase 3: p (already in acc1) -> bf16, overwrite kq ----
#pragma unroll
    for (int rg = 0; rg < 2; rg++) {
#pragma unroll
        for (int reg = 0; reg < 4; reg++) {
            int r = rg * 16 + q4 * 4 + reg;
#pragma unroll
            for (int nt = 0; nt < 4; nt++) {
                int col = (w << 6) + nt * 16 + li;
                *(unsigned short*)(kq + r * KQ_STRIDE + col * 2) = f2bf(acc1[rg * 4 + nt][reg]);
            }
        }
    }
    __syncthreads();

    // ---- phase 4: PV GEMM, 32 rows x out cols [w*64, +64) ----
    floatx4 acc2[8];
#pragma unroll
    for (int i = 0; i < 8; i++) acc2[i] = (floatx4){0.f, 0.f, 0.f, 0.f};
    {
        const short8* vf = (const short8*)valsFrag;
        short8 bcur[4], bnxt[4];
#pragma unroll
        for (int nt = 0; nt < 4; nt++) bcur[nt] = vf[(size_t)((w * 4 + nt) * 64 + l)];
        for (int kt = 0; kt < 16; kt++) {
            if (kt < 15) {
#pragma unroll
                for (int nt = 0; nt < 4; nt++)
                    bnxt[nt] = vf[(size_t)(((kt + 1) * 32 + w * 4 + nt) * 64 + l)];
            }
            short8 a[2];
#pragma unroll
            for (int rg = 0; rg < 2; rg++)
                a[rg] = *(const short8*)(kq + (rg * 16 + li) * KQ_STRIDE + kt * 64 + q4 * 16);
#pragma unroll
            for (int rg = 0; rg < 2; rg++)
#pragma unroll
                for (int nt = 0; nt < 4; nt++)
                    acc2[rg * 4 + nt] = __builtin_amdgcn_mfma_f32_16x16x32_bf16(
                        a[rg], bcur[nt], acc2[rg * 4 + nt], 0, 0, 0);
#pragma unroll
            for (int nt = 0; nt < 4; nt++) bcur[nt] = bnxt[nt];
        }
    }

    // ---- phase 4b: cross-wave merge, every wave redundantly; lane l owns row l&31 ----
    unsigned K; float z1, e1, z2;
    {
        const int lr = l & 31;
        floatx4 v = *(const floatx4*)stats[0][lr];
        K = __builtin_bit_cast(unsigned, v[0]); z1 = v[1]; e1 = v[2]; z2 = v[3];
#pragma unroll
        for (int p = 1; p < 8; p++) {
            floatx4 u = *(const floatx4*)stats[p][lr];
            unsigned Ko = __builtin_bit_cast(unsigned, u[0]);
            K = Ko > K ? Ko : K;
            z1 += u[1]; e1 += u[2]; z2 += u[3];
        }
    }
    const float iz = 1.0f / z1;
    const int myidx = 511 - (int)(K & 0x1FFu);

    // all waves must be done reading the p tile before we reuse kq as store stage
    __syncthreads();

    // ---- phase 5: scale by 1/Z1, bounce through wave-private LDS, float4 stores ----
    {
        float* ws = (float*)kq + w * 1024;           // 4 KB per wave, wave-private
#pragma unroll
        for (int rg = 0; rg < 2; rg++) {
#pragma unroll
            for (int reg = 0; reg < 4; reg++) {
                int lr = q4 * 4 + reg;               // local row within 16-row group
                float izr = __shfl(iz, rg * 16 + lr, 64);
#pragma unroll
                for (int nt = 0; nt < 4; nt++)
                    ws[lr * 64 + nt * 16 + li] = acc2[rg * 4 + nt][reg] * izr;
            }
            // read back coalesced: 4 rows per iter, 16 lanes x float4 per row
#pragma unroll
            for (int j = 0; j < 4; j++) {
                int lr = j * 4 + q4;
                float4 val = *(const float4*)&ws[lr * 64 + li * 4];
                *(float4*)(outRQ + (size_t)(row0 + rg * 16 + lr) * C_DIM + (w << 6) + li * 4) = val;
            }
        }
    }

    // ---- phase 6: fused gathering loss: mean((q_norm - values[idx])^2) ----
    float gacc = 0.f;
#pragma unroll
    for (int rr = 0; rr < 4; rr++) {
        int r = (w << 2) + rr;
        int idxr = __shfl(myidx, r, 64);
        const float4* qr = (const float4*)(query + (size_t)(row0 + r) * C_DIM);
        float4 a = qr[l * 2], b = qr[l * 2 + 1];
        float ss = a.x * a.x + a.y * a.y + a.z * a.z + a.w * a.w +
                   b.x * b.x + b.y * b.y + b.z * b.z + b.w * b.w;
#pragma unroll
        for (int m = 1; m < 64; m <<= 1) ss += __shfl_xor(ss, m, 64);
        float inv = 1.0f / fmaxf(sqrtf(ss), 1e-12f);
        const float4* vr = (const float4*)(values + (size_t)idxr * C_DIM);
        float4 va = vr[l * 2], vb = vr[l * 2 + 1];
        float d;
        d = a.x * inv - va.x; gacc += d * d;
        d = a.y * inv - va.y; gacc += d * d;
        d = a.z * inv - va.z; gacc += d * d;
        d = a.w * inv - va.w; gacc += d * d;
        d = b.x * inv - vb.x; gacc += d * d;
        d = b.y * inv - vb.y; gacc += d * d;
        d = b.z * inv - vb.z; gacc += d * d;
        d = b.w * inv - vb.w; gacc += d * d;
    }
#pragma unroll
    for (int m = 1; m < 64; m <<= 1) gacc += __shfl_xor(gacc, m, 64);
    if (l == 0) gpart[w] = gacc;

    // ---- phase 7: scalars (wave 0 only), rows 0..31 live on lanes 0..31 ----
    if (w == 0) {
        unsigned um = (K >> 31) ? (K & 0x7FFFFFFFu) : ~K;
        um &= ~0x1FFu;
        float m1 = __builtin_bit_cast(float, um);         // ~max s for this row
        float ent = __logf(z1) - e1 * iz;                 // logZ - E[s]
        float con = __logf(z2) - 2.0f * m1;               // -logp[idx] of logits = 2s
#pragma unroll
        for (int msk = 1; msk < 32; msk <<= 1) {          // sum rows 0..31 on lane 0
            ent += __shfl_xor(ent, msk, 64);
            con += __shfl_xor(con, msk, 64);
        }
        if (l == 0) {
            atomicAdd(&scal[0], ent * (1.0f / 32768.0f));
            atomicAdd(&scal[2], con * (1.0f / 12800.0f));
        }
    }
    __syncthreads();
    if (tid == 0) {
        float s = 0.f;
#pragma unroll
        for (int i = 0; i < 8; i++) s += gpart[i];
        atomicAdd(&scal[1], s * (1.0f / (32768.0f * 512.0f)));
    }
}

extern "C" void kernel_launch(void* const* d_in, const int* in_sizes, int n_in,
                              void* d_out, int out_size, void* d_ws, size_t ws_size,
                              hipStream_t stream) {
    (void)in_sizes; (void)n_in; (void)out_size; (void)ws_size;
    const float* key    = (const float*)d_in[0];
    const float* query  = (const float*)d_in[1];
    const float* keysIn = (const float*)d_in[2];
    const float* valsIn = (const float*)d_in[3];
    float* out = (float*)d_out;

    unsigned short* keysFrag = (unsigned short*)d_ws;            // 512 KB
    unsigned short* valsFrag = keysFrag + 512 * 512;             // 512 KB

    float* outRQ   = out;                       // 16777216 floats
    float* scal    = out + 16777216;            // entropy, gathering, contrast
    float* keysOut = out + 16777219;            // 262144 floats
    float* valsOut = keysOut + 262144;          // 262144 floats

    pack_kernel<<<384, 256, 0, stream>>>(keysIn, valsIn, keysFrag, valsFrag,
                                         keysOut, valsOut, scal);
    fused_kernel<<<1024, 512, 0, stream>>>(key, query, keysFrag, valsFrag, valsIn, outRQ, scal);
}

// Round 4
// 247.204 us; speedup vs baseline: 1.1564x; 1.1564x over previous
//
#include <hip/hip_runtime.h>

typedef short short8 __attribute__((ext_vector_type(8)));
typedef float floatx4 __attribute__((ext_vector_type(4)));

#define C_DIM 512
#define KQ_STRIDE 1040   // bytes per row of the LDS k/p tile (512*2 + 16 pad)

__device__ __forceinline__ unsigned short f2bf(float f) {
    unsigned u = __builtin_bit_cast(unsigned, f);
    u = u + 0x7fffu + ((u >> 16) & 1u);
    return (unsigned short)(u >> 16);
}

// Monotone uint key for argmax: order-preserving encoding of float s, with the
// 9 low bits replaced by (511-col) so uint-max == (max s, then min col) to the
// granularity of 9 truncated mantissa bits (~2.4e-4 on m; only feeds scalars).
__device__ __forceinline__ unsigned skey(float s, int col) {
    unsigned u = __builtin_bit_cast(unsigned, s);
    u = ((int)u < 0) ? ~u : (u | 0x80000000u);
    return (u & ~0x1FFu) | (unsigned)(511 - col);
}

// ---------------- pack kernel: keys -> B-frag order (score GEMM), values -> B-frag
// order (PV GEMM), plus passthrough copies of keys/values and scal zeroing.
// B fragment for mfma_f32_16x16x32_bf16: lane l holds B[k=(l>>4)*8+j][n=l&15], j=0..7
__global__ __launch_bounds__(256) void pack_kernel(
    const float* __restrict__ keys, const float* __restrict__ values,
    unsigned short* __restrict__ keysFrag, unsigned short* __restrict__ valsFrag,
    float* __restrict__ keysOut, float* __restrict__ valsOut,
    float* __restrict__ scal) {
    int tid = blockIdx.x * 256 + threadIdx.x;
    if (tid < 65536) {
        int e  = tid & 32767;
        int l  = e & 63;
        int NT = (e >> 6) & 31;
        int kt = e >> 11;                           // 0..15
        int li = l & 15, q4 = l >> 4;
        unsigned short tmp[8];
        if (tid < 32768) {
            // score GEMM: B[k][n] = keys[n][k], keys is [M, C] row-major
            const float* s = keys + (size_t)(NT * 16 + li) * C_DIM + kt * 32 + q4 * 8;
#pragma unroll
            for (int j = 0; j < 8; j++) tmp[j] = f2bf(s[j]);
            unsigned short* d = keysFrag + ((size_t)(kt * 32 + NT) * 64 + l) * 8;
            *(ushort4*)d       = make_ushort4(tmp[0], tmp[1], tmp[2], tmp[3]);
            *(ushort4*)(d + 4) = make_ushort4(tmp[4], tmp[5], tmp[6], tmp[7]);
        } else {
            // PV GEMM: B[k][n] = values[k][n], k indexes M
#pragma unroll
            for (int j = 0; j < 8; j++)
                tmp[j] = f2bf(values[(size_t)(kt * 32 + q4 * 8 + j) * C_DIM + NT * 16 + li]);
            unsigned short* d = valsFrag + ((size_t)(kt * 32 + NT) * 64 + l) * 8;
            *(ushort4*)d       = make_ushort4(tmp[0], tmp[1], tmp[2], tmp[3]);
            *(ushort4*)(d + 4) = make_ushort4(tmp[4], tmp[5], tmp[6], tmp[7]);
        }
    } else {
        int ct = tid - 65536;                       // 0..32767
        if (ct == 0) { scal[0] = 0.f; scal[1] = 0.f; scal[2] = 0.f; }
#pragma unroll
        for (int i = 0; i < 4; i++) {
            int idx = ct + i * 32768;               // 0..131071 float4s
            if (idx < 65536) ((float4*)keysOut)[idx] = ((const float4*)keys)[idx];
            else             ((float4*)valsOut)[idx - 65536] = ((const float4*)values)[idx - 65536];
        }
    }
}

// ---------------- fused main kernel: 64 rows per block, 512 threads (8 waves)
// Round-2 structure (known 121us) with ONE change: B-frag register prefetch
// deepened to 2 kt ahead in both GEMMs (12 global loads in flight instead of 4-8)
// to cover L2 latency that the 1-deep pipeline exposed.
__global__ __launch_bounds__(512, 4) void fused_kernel(
    const float* __restrict__ key,
    const float* __restrict__ query,
    const unsigned short* __restrict__ keysFrag,
    const unsigned short* __restrict__ valsFrag,
    const float* __restrict__ values,
    float* __restrict__ outRQ,
    float* __restrict__ scal) {   // [0]=entropy, [1]=gather, [2]=contrast
    __shared__ char kq[64 * KQ_STRIDE];             // k bf16 tile, later reused as p tile
    __shared__ __align__(16) float stats[8][64][4]; // [wave][row][key,z1,e1,z2]
    __shared__ float gpart[8];

    const int tid = threadIdx.x;
    const int w  = tid >> 6;
    const int l  = tid & 63;
    const int li = l & 15;
    const int q4 = l >> 4;
    const int row0 = blockIdx.x << 6;

    // ---- phase 0: load 8 rows/wave, l2-normalize, write bf16 to LDS ----
#pragma unroll
    for (int it = 0; it < 2; it++) {
        int r = (w << 3) + (it << 2) + q4;                      // 16 lanes per row
        const float4* src = (const float4*)(key + (size_t)(row0 + r) * C_DIM);
        float4 v[8];
        float ss = 0.f;
#pragma unroll
        for (int i = 0; i < 8; i++) {
            v[i] = src[i * 16 + li];
            ss += v[i].x * v[i].x + v[i].y * v[i].y + v[i].z * v[i].z + v[i].w * v[i].w;
        }
#pragma unroll
        for (int m = 1; m < 16; m <<= 1) ss += __shfl_xor(ss, m, 64);
        float inv = 1.0f / fmaxf(sqrtf(ss), 1e-12f);
        char* dstrow = kq + r * KQ_STRIDE;
#pragma unroll
        for (int i = 0; i < 8; i++) {
            ushort4 b = make_ushort4(f2bf(v[i].x * inv), f2bf(v[i].y * inv),
                                     f2bf(v[i].z * inv), f2bf(v[i].w * inv));
            *(ushort4*)(dstrow + i * 128 + li * 8) = b;
        }
    }
    __syncthreads();

    // ---- phase 1: score GEMM, 64 rows x cols [w*64, +64), B prefetched TWO kt ahead ----
    floatx4 acc1[16];                        // [rg*4+nt]
#pragma unroll
    for (int i = 0; i < 16; i++) acc1[i] = (floatx4){0.f, 0.f, 0.f, 0.f};
    {
        const short8* kf = (const short8*)keysFrag;
        short8 b0[4], b1[4], b2[4];
#pragma unroll
        for (int nt = 0; nt < 4; nt++) b0[nt] = kf[(size_t)((w * 4 + nt) * 64 + l)];
#pragma unroll
        for (int nt = 0; nt < 4; nt++) b1[nt] = kf[(size_t)((32 + w * 4 + nt) * 64 + l)];
        for (int kt = 0; kt < 16; kt++) {
            if (kt < 14) {
#pragma unroll
                for (int nt = 0; nt < 4; nt++)
                    b2[nt] = kf[(size_t)(((kt + 2) * 32 + w * 4 + nt) * 64 + l)];
            }
            short8 a[4];
#pragma unroll
            for (int rg = 0; rg < 4; rg++)
                a[rg] = *(const short8*)(kq + (rg * 16 + li) * KQ_STRIDE + kt * 64 + q4 * 16);
#pragma unroll
            for (int rg = 0; rg < 4; rg++)
#pragma unroll
                for (int nt = 0; nt < 4; nt++)
                    acc1[rg * 4 + nt] = __builtin_amdgcn_mfma_f32_16x16x32_bf16(
                        a[rg], b0[nt], acc1[rg * 4 + nt], 0, 0, 0);
#pragma unroll
            for (int nt = 0; nt < 4; nt++) { b0[nt] = b1[nt]; b1[nt] = b2[nt]; }
        }
    }

    // ---- phase 2: per-row partial stats (shiftless), overwrite acc1 with p ----
    // C layout: col = li, row = q4*4 + reg.
#pragma unroll
    for (int rg = 0; rg < 4; rg++) {
#pragma unroll
        for (int reg = 0; reg < 4; reg++) {
            const int colbase = (w << 6) + li;
            float s0 = acc1[rg * 4 + 0][reg];
            float s1 = acc1[rg * 4 + 1][reg];
            float s2 = acc1[rg * 4 + 2][reg];
            float s3 = acc1[rg * 4 + 3][reg];
            unsigned K  = skey(s0, colbase);
            unsigned K1 = skey(s1, colbase + 16);
            unsigned K2 = skey(s2, colbase + 32);
            unsigned K3 = skey(s3, colbase + 48);
            K = K1 > K ? K1 : K;
            K = K2 > K ? K2 : K;
            K = K3 > K ? K3 : K;
            float p0 = __expf(s0), p1 = __expf(s1), p2 = __expf(s2), p3 = __expf(s3);
            float z1 = (p0 + p1) + (p2 + p3);
            float e1 = p0 * s0 + p1 * s1 + p2 * s2 + p3 * s3;
            float z2 = p0 * p0 + p1 * p1 + p2 * p2 + p3 * p3;
            acc1[rg * 4 + 0][reg] = p0;
            acc1[rg * 4 + 1][reg] = p1;
            acc1[rg * 4 + 2][reg] = p2;
            acc1[rg * 4 + 3][reg] = p3;
#pragma unroll
            for (int msk = 1; msk < 16; msk <<= 1) {
                unsigned Ko = __shfl_xor(K, msk, 64);
                z1 += __shfl_xor(z1, msk, 64);
                e1 += __shfl_xor(e1, msk, 64);
                z2 += __shfl_xor(z2, msk, 64);
                K = Ko > K ? Ko : K;
            }
            if (li == 0) {
                floatx4 sv;
                sv[0] = __builtin_bit_cast(float, K);
                sv[1] = z1; sv[2] = e1; sv[3] = z2;
                *(floatx4*)stats[w][rg * 16 + q4 * 4 + reg] = sv;
            }
        }
    }
    __syncthreads();

    // ---- phase 3: p (already in acc1) -> bf16, overwrite kq ----
#pragma unroll
    for (int rg = 0; rg < 4; rg++) {
#pragma unroll
        for (int reg = 0; reg < 4; reg++) {
            int r = rg * 16 + q4 * 4 + reg;
#pragma unroll
            for (int nt = 0; nt < 4; nt++) {
                int col = (w << 6) + nt * 16 + li;
                *(unsigned short*)(kq + r * KQ_STRIDE + col * 2) = f2bf(acc1[rg * 4 + nt][reg]);
            }
        }
    }
    __syncthreads();

    // ---- phase 4: PV GEMM, 64 rows x out cols [w*64, +64), B prefetched TWO kt ahead ----
    floatx4 acc2[16];
#pragma unroll
    for (int i = 0; i < 16; i++) acc2[i] = (floatx4){0.f, 0.f, 0.f, 0.f};
    {
        const short8* vf = (const short8*)valsFrag;
        short8 b0[4], b1[4], b2[4];
#pragma unroll
        for (int nt = 0; nt < 4; nt++) b0[nt] = vf[(size_t)((w * 4 + nt) * 64 + l)];
#pragma unroll
        for (int nt = 0; nt < 4; nt++) b1[nt] = vf[(size_t)((32 + w * 4 + nt) * 64 + l)];
        for (int kt = 0; kt < 16; kt++) {
            if (kt < 14) {
#pragma unroll
                for (int nt = 0; nt < 4; nt++)
                    b2[nt] = vf[(size_t)(((kt + 2) * 32 + w * 4 + nt) * 64 + l)];
            }
            short8 a[4];
#pragma unroll
            for (int rg = 0; rg < 4; rg++)
                a[rg] = *(const short8*)(kq + (rg * 16 + li) * KQ_STRIDE + kt * 64 + q4 * 16);
#pragma unroll
            for (int rg = 0; rg < 4; rg++)
#pragma unroll
                for (int nt = 0; nt < 4; nt++)
                    acc2[rg * 4 + nt] = __builtin_amdgcn_mfma_f32_16x16x32_bf16(
                        a[rg], b0[nt], acc2[rg * 4 + nt], 0, 0, 0);
#pragma unroll
            for (int nt = 0; nt < 4; nt++) { b0[nt] = b1[nt]; b1[nt] = b2[nt]; }
        }
    }

    // ---- phase 4b: cross-wave merge, every wave redundantly; lane l owns row l ----
    unsigned K; float z1, e1, z2;
    {
        floatx4 v = *(const floatx4*)stats[0][l];
        K = __builtin_bit_cast(unsigned, v[0]); z1 = v[1]; e1 = v[2]; z2 = v[3];
#pragma unroll
        for (int p = 1; p < 8; p++) {
            floatx4 u = *(const floatx4*)stats[p][l];
            unsigned Ko = __builtin_bit_cast(unsigned, u[0]);
            K = Ko > K ? Ko : K;
            z1 += u[1]; e1 += u[2]; z2 += u[3];
        }
    }
    const float iz = 1.0f / z1;
    const int myidx = 511 - (int)(K & 0x1FFu);

    // ---- phase 5: scale by 1/Z1 (shfl from owner lane) and store ----
#pragma unroll
    for (int rg = 0; rg < 4; rg++) {
#pragma unroll
        for (int reg = 0; reg < 4; reg++) {
            int r = rg * 16 + q4 * 4 + reg;
            float izr = __shfl(iz, r, 64);
            float* orow = outRQ + (size_t)(row0 + r) * C_DIM + (w << 6) + li;
#pragma unroll
            for (int nt = 0; nt < 4; nt++) orow[nt * 16] = acc2[rg * 4 + nt][reg] * izr;
        }
    }

    // ---- phase 6: fused gathering loss: mean((q_norm - values[idx])^2) ----
    float gacc = 0.f;
#pragma unroll
    for (int rr = 0; rr < 8; rr++) {
        int r = (w << 3) + rr;
        int idxr = __shfl(myidx, r, 64);
        const float4* qr = (const float4*)(query + (size_t)(row0 + r) * C_DIM);
        float4 a = qr[l * 2], b = qr[l * 2 + 1];
        float ss = a.x * a.x + a.y * a.y + a.z * a.z + a.w * a.w +
                   b.x * b.x + b.y * b.y + b.z * b.z + b.w * b.w;
#pragma unroll
        for (int m = 1; m < 64; m <<= 1) ss += __shfl_xor(ss, m, 64);
        float inv = 1.0f / fmaxf(sqrtf(ss), 1e-12f);
        const float4* vr = (const float4*)(values + (size_t)idxr * C_DIM);
        float4 va = vr[l * 2], vb = vr[l * 2 + 1];
        float d;
        d = a.x * inv - va.x; gacc += d * d;
        d = a.y * inv - va.y; gacc += d * d;
        d = a.z * inv - va.z; gacc += d * d;
        d = a.w * inv - va.w; gacc += d * d;
        d = b.x * inv - vb.x; gacc += d * d;
        d = b.y * inv - vb.y; gacc += d * d;
        d = b.z * inv - vb.z; gacc += d * d;
        d = b.w * inv - vb.w; gacc += d * d;
    }
#pragma unroll
    for (int m = 1; m < 64; m <<= 1) gacc += __shfl_xor(gacc, m, 64);
    if (l == 0) gpart[w] = gacc;

    // ---- phase 7: scalars (wave 0 only), off the critical path ----
    if (w == 0) {
        unsigned um = (K >> 31) ? (K & 0x7FFFFFFFu) : ~K;
        um &= ~0x1FFu;
        float m1 = __builtin_bit_cast(float, um);         // ~max s for this row
        float ent = __logf(z1) - e1 * iz;                 // logZ - E[s]
        float con = __logf(z2) - 2.0f * m1;               // -logp[idx] of logits = 2s
#pragma unroll
        for (int msk = 1; msk < 64; msk <<= 1) {
            ent += __shfl_xor(ent, msk, 64);
            con += __shfl_xor(con, msk, 64);
        }
        if (l == 0) {
            atomicAdd(&scal[0], ent * (1.0f / 32768.0f));
            atomicAdd(&scal[2], con * (1.0f / 12800.0f));
        }
    }
    __syncthreads();
    if (tid == 0) {
        float s = 0.f;
#pragma unroll
        for (int i = 0; i < 8; i++) s += gpart[i];
        atomicAdd(&scal[1], s * (1.0f / (32768.0f * 512.0f)));
    }
}

extern "C" void kernel_launch(void* const* d_in, const int* in_sizes, int n_in,
                              void* d_out, int out_size, void* d_ws, size_t ws_size,
                              hipStream_t stream) {
    (void)in_sizes; (void)n_in; (void)out_size; (void)ws_size;
    const float* key    = (const float*)d_in[0];
    const float* query  = (const float*)d_in[1];
    const float* keysIn = (const float*)d_in[2];
    const float* valsIn = (const float*)d_in[3];
    float* out = (float*)d_out;

    unsigned short* keysFrag = (unsigned short*)d_ws;            // 512 KB
    unsigned short* valsFrag = keysFrag + 512 * 512;             // 512 KB

    float* outRQ   = out;                       // 16777216 floats
    float* scal    = out + 16777216;            // entropy, gathering, contrast
    float* keysOut = out + 16777219;            // 262144 floats
    float* valsOut = keysOut + 262144;          // 262144 floats

    pack_kernel<<<384, 256, 0, stream>>>(keysIn, valsIn, keysFrag, valsFrag,
                                         keysOut, valsOut, scal);
    fused_kernel<<<512, 512, 0, stream>>>(key, query, keysFrag, valsFrag, valsIn, outRQ, scal);
}

// Round 5
// 239.852 us; speedup vs baseline: 1.1919x; 1.0307x over previous
//
#include <hip/hip_runtime.h>

typedef short short8 __attribute__((ext_vector_type(8)));
typedef float floatx4 __attribute__((ext_vector_type(4)));

#define C_DIM 512
#define KQ_STRIDE 1040   // bytes per row of the LDS k/p tile (512*2 + 16 pad)

__device__ __forceinline__ unsigned short f2bf(float f) {
    unsigned u = __builtin_bit_cast(unsigned, f);
    u = u + 0x7fffu + ((u >> 16) & 1u);
    return (unsigned short)(u >> 16);
}

// Monotone uint key for argmax (max s, then min col); 9 low bits carry 511-col.
__device__ __forceinline__ unsigned skey(float s, int col) {
    unsigned u = __builtin_bit_cast(unsigned, s);
    u = ((int)u < 0) ? ~u : (u | 0x80000000u);
    return (u & ~0x1FFu) | (unsigned)(511 - col);
}

// ---- DPP 16-lane-row reductions: VALU pipe instead of ds_swizzle (DS pipe) ----
// ctrls: 0xB1 quad_perm[1,0,3,2] (xor1), 0x4E quad_perm[2,3,0,1] (xor2),
//        0x124 row_ror:4, 0x128 row_ror:8. After all 4 steps every lane of the
//        16-lane row holds the full row reduction.
template <int CTRL>
__device__ __forceinline__ float dppAddF(float x) {
    int t = __builtin_amdgcn_update_dpp(0, __builtin_bit_cast(int, x), CTRL, 0xF, 0xF, true);
    return x + __builtin_bit_cast(float, t);
}
template <int CTRL>
__device__ __forceinline__ unsigned dppMaxU(unsigned x) {
    unsigned u = (unsigned)__builtin_amdgcn_update_dpp(0, (int)x, CTRL, 0xF, 0xF, true);
    return u > x ? u : x;
}
__device__ __forceinline__ float rowAdd16(float x) {
    x = dppAddF<0xB1>(x);
    x = dppAddF<0x4E>(x);
    x = dppAddF<0x124>(x);
    x = dppAddF<0x128>(x);
    return x;
}

// ---------------- pack kernel: keys/values -> B-frag order + passthrough copies + scal zero
__global__ __launch_bounds__(256) void pack_kernel(
    const float* __restrict__ keys, const float* __restrict__ values,
    unsigned short* __restrict__ keysFrag, unsigned short* __restrict__ valsFrag,
    float* __restrict__ keysOut, float* __restrict__ valsOut,
    float* __restrict__ scal) {
    int tid = blockIdx.x * 256 + threadIdx.x;
    if (tid < 65536) {
        int e  = tid & 32767;
        int l  = e & 63;
        int NT = (e >> 6) & 31;
        int kt = e >> 11;                           // 0..15
        int li = l & 15, q4 = l >> 4;
        unsigned short tmp[8];
        if (tid < 32768) {
            // score GEMM: B[k][n] = keys[n][k], keys is [M, C] row-major
            const float* s = keys + (size_t)(NT * 16 + li) * C_DIM + kt * 32 + q4 * 8;
#pragma unroll
            for (int j = 0; j < 8; j++) tmp[j] = f2bf(s[j]);
            unsigned short* d = keysFrag + ((size_t)(kt * 32 + NT) * 64 + l) * 8;
            *(ushort4*)d       = make_ushort4(tmp[0], tmp[1], tmp[2], tmp[3]);
            *(ushort4*)(d + 4) = make_ushort4(tmp[4], tmp[5], tmp[6], tmp[7]);
        } else {
            // PV GEMM: B[k][n] = values[k][n], k indexes M
#pragma unroll
            for (int j = 0; j < 8; j++)
                tmp[j] = f2bf(values[(size_t)(kt * 32 + q4 * 8 + j) * C_DIM + NT * 16 + li]);
            unsigned short* d = valsFrag + ((size_t)(kt * 32 + NT) * 64 + l) * 8;
            *(ushort4*)d       = make_ushort4(tmp[0], tmp[1], tmp[2], tmp[3]);
            *(ushort4*)(d + 4) = make_ushort4(tmp[4], tmp[5], tmp[6], tmp[7]);
        }
    } else {
        int ct = tid - 65536;                       // 0..32767
        if (ct == 0) { scal[0] = 0.f; scal[1] = 0.f; scal[2] = 0.f; }
#pragma unroll
        for (int i = 0; i < 4; i++) {
            int idx = ct + i * 32768;               // 0..131071 float4s
            if (idx < 65536) ((float4*)keysOut)[idx] = ((const float4*)keys)[idx];
            else             ((float4*)valsOut)[idx - 65536] = ((const float4*)values)[idx - 65536];
        }
    }
}

// ---------------- fused main kernel: 64 rows per block, 512 threads (8 waves)
// R2 structure (121us) + (a) query L3-warm touch at start so phase 6's 64MB read
// overlaps the GEMM/stat phases, (b) all width-16 reductions moved from
// ds_swizzle (DS pipe, contended with GEMM ds_reads) to DPP on the idle VALU.
__global__ __launch_bounds__(512, 4) void fused_kernel(
    const float* __restrict__ key,
    const float* __restrict__ query,
    const unsigned short* __restrict__ keysFrag,
    const unsigned short* __restrict__ valsFrag,
    const float* __restrict__ values,
    float* __restrict__ outRQ,
    float* __restrict__ scal) {   // [0]=entropy, [1]=gather, [2]=contrast
    __shared__ char kq[64 * KQ_STRIDE];             // k bf16 tile, later reused as p tile
    __shared__ __align__(16) float stats[8][64][4]; // [wave][row][key,z1,e1,z2]
    __shared__ float gpart[8];

    const int tid = threadIdx.x;
    const int w  = tid >> 6;
    const int l  = tid & 63;
    const int li = l & 15;
    const int q4 = l >> 4;
    const int row0 = blockIdx.x << 6;

    // ---- query L3-warm touch: 1 float per 128B line of this block's query slice ----
    const float* qtb = query + (size_t)row0 * C_DIM;
    float tch0 = qtb[(tid * 2) * 32];
    float tch1 = qtb[(tid * 2 + 1) * 32];

    // ---- phase 0: load 8 rows/wave, l2-normalize, write bf16 to LDS ----
#pragma unroll
    for (int it = 0; it < 2; it++) {
        int r = (w << 3) + (it << 2) + q4;                      // 16 lanes per row
        const float4* src = (const float4*)(key + (size_t)(row0 + r) * C_DIM);
        float4 v[8];
        float ss = 0.f;
#pragma unroll
        for (int i = 0; i < 8; i++) {
            v[i] = src[i * 16 + li];
            ss += v[i].x * v[i].x + v[i].y * v[i].y + v[i].z * v[i].z + v[i].w * v[i].w;
        }
        ss = rowAdd16(ss);
        float inv = 1.0f / fmaxf(sqrtf(ss), 1e-12f);
        char* dstrow = kq + r * KQ_STRIDE;
#pragma unroll
        for (int i = 0; i < 8; i++) {
            ushort4 b = make_ushort4(f2bf(v[i].x * inv), f2bf(v[i].y * inv),
                                     f2bf(v[i].z * inv), f2bf(v[i].w * inv));
            *(ushort4*)(dstrow + i * 128 + li * 8) = b;
        }
    }
    // keep touches alive (loads already retired together with key loads)
    asm volatile("" :: "v"(tch0), "v"(tch1));
    __syncthreads();

    // ---- phase 1: score GEMM, 64 rows x cols [w*64, +64), B prefetched one kt ahead ----
    floatx4 acc1[16];                        // [rg*4+nt]
#pragma unroll
    for (int i = 0; i < 16; i++) acc1[i] = (floatx4){0.f, 0.f, 0.f, 0.f};
    {
        const short8* kf = (const short8*)keysFrag;
        short8 bcur[4], bnxt[4];
#pragma unroll
        for (int nt = 0; nt < 4; nt++) bcur[nt] = kf[(size_t)((w * 4 + nt) * 64 + l)];
        for (int kt = 0; kt < 16; kt++) {
            if (kt < 15) {
#pragma unroll
                for (int nt = 0; nt < 4; nt++)
                    bnxt[nt] = kf[(size_t)(((kt + 1) * 32 + w * 4 + nt) * 64 + l)];
            }
            short8 a[4];
#pragma unroll
            for (int rg = 0; rg < 4; rg++)
                a[rg] = *(const short8*)(kq + (rg * 16 + li) * KQ_STRIDE + kt * 64 + q4 * 16);
#pragma unroll
            for (int rg = 0; rg < 4; rg++)
#pragma unroll
                for (int nt = 0; nt < 4; nt++)
                    acc1[rg * 4 + nt] = __builtin_amdgcn_mfma_f32_16x16x32_bf16(
                        a[rg], bcur[nt], acc1[rg * 4 + nt], 0, 0, 0);
#pragma unroll
            for (int nt = 0; nt < 4; nt++) bcur[nt] = bnxt[nt];
        }
    }

    // ---- phase 2: per-row partial stats (shiftless, DPP reductions), acc1 -> p ----
    // C layout: col = li, row = q4*4 + reg.
#pragma unroll
    for (int rg = 0; rg < 4; rg++) {
#pragma unroll
        for (int reg = 0; reg < 4; reg++) {
            const int colbase = (w << 6) + li;
            float s0 = acc1[rg * 4 + 0][reg];
            float s1 = acc1[rg * 4 + 1][reg];
            float s2 = acc1[rg * 4 + 2][reg];
            float s3 = acc1[rg * 4 + 3][reg];
            unsigned K  = skey(s0, colbase);
            unsigned K1 = skey(s1, colbase + 16);
            unsigned K2 = skey(s2, colbase + 32);
            unsigned K3 = skey(s3, colbase + 48);
            K = K1 > K ? K1 : K;
            K = K2 > K ? K2 : K;
            K = K3 > K ? K3 : K;
            float p0 = __expf(s0), p1 = __expf(s1), p2 = __expf(s2), p3 = __expf(s3);
            float z1 = (p0 + p1) + (p2 + p3);
            float e1 = p0 * s0 + p1 * s1 + p2 * s2 + p3 * s3;
            float z2 = p0 * p0 + p1 * p1 + p2 * p2 + p3 * p3;
            acc1[rg * 4 + 0][reg] = p0;
            acc1[rg * 4 + 1][reg] = p1;
            acc1[rg * 4 + 2][reg] = p2;
            acc1[rg * 4 + 3][reg] = p3;
            // 16-lane reduction entirely on VALU via DPP
            K = dppMaxU<0xB1>(K);  z1 = dppAddF<0xB1>(z1);  e1 = dppAddF<0xB1>(e1);  z2 = dppAddF<0xB1>(z2);
            K = dppMaxU<0x4E>(K);  z1 = dppAddF<0x4E>(z1);  e1 = dppAddF<0x4E>(e1);  z2 = dppAddF<0x4E>(z2);
            K = dppMaxU<0x124>(K); z1 = dppAddF<0x124>(z1); e1 = dppAddF<0x124>(e1); z2 = dppAddF<0x124>(z2);
            K = dppMaxU<0x128>(K); z1 = dppAddF<0x128>(z1); e1 = dppAddF<0x128>(e1); z2 = dppAddF<0x128>(z2);
            if (li == 0) {
                floatx4 sv;
                sv[0] = __builtin_bit_cast(float, K);
                sv[1] = z1; sv[2] = e1; sv[3] = z2;
                *(floatx4*)stats[w][rg * 16 + q4 * 4 + reg] = sv;
            }
        }
    }
    __syncthreads();

    // ---- phase 3: p (already in acc1) -> bf16, overwrite kq ----
#pragma unroll
    for (int rg = 0; rg < 4; rg++) {
#pragma unroll
        for (int reg = 0; reg < 4; reg++) {
            int r = rg * 16 + q4 * 4 + reg;
#pragma unroll
            for (int nt = 0; nt < 4; nt++) {
                int col = (w << 6) + nt * 16 + li;
                *(unsigned short*)(kq + r * KQ_STRIDE + col * 2) = f2bf(acc1[rg * 4 + nt][reg]);
            }
        }
    }
    __syncthreads();

    // ---- phase 4: PV GEMM, 64 rows x out cols [w*64, +64) ----
    floatx4 acc2[16];
#pragma unroll
    for (int i = 0; i < 16; i++) acc2[i] = (floatx4){0.f, 0.f, 0.f, 0.f};
    {
        const short8* vf = (const short8*)valsFrag;
        short8 bcur[4], bnxt[4];
#pragma unroll
        for (int nt = 0; nt < 4; nt++) bcur[nt] = vf[(size_t)((w * 4 + nt) * 64 + l)];
        for (int kt = 0; kt < 16; kt++) {
            if (kt < 15) {
#pragma unroll
                for (int nt = 0; nt < 4; nt++)
                    bnxt[nt] = vf[(size_t)(((kt + 1) * 32 + w * 4 + nt) * 64 + l)];
            }
            short8 a[4];
#pragma unroll
            for (int rg = 0; rg < 4; rg++)
                a[rg] = *(const short8*)(kq + (rg * 16 + li) * KQ_STRIDE + kt * 64 + q4 * 16);
#pragma unroll
            for (int rg = 0; rg < 4; rg++)
#pragma unroll
                for (int nt = 0; nt < 4; nt++)
                    acc2[rg * 4 + nt] = __builtin_amdgcn_mfma_f32_16x16x32_bf16(
                        a[rg], bcur[nt], acc2[rg * 4 + nt], 0, 0, 0);
#pragma unroll
            for (int nt = 0; nt < 4; nt++) bcur[nt] = bnxt[nt];
        }
    }

    // ---- phase 4b: cross-wave merge, every wave redundantly; lane l owns row l ----
    unsigned K; float z1, e1, z2;
    {
        floatx4 v = *(const floatx4*)stats[0][l];
        K = __builtin_bit_cast(unsigned, v[0]); z1 = v[1]; e1 = v[2]; z2 = v[3];
#pragma unroll
        for (int p = 1; p < 8; p++) {
            floatx4 u = *(const floatx4*)stats[p][l];
            unsigned Ko = __builtin_bit_cast(unsigned, u[0]);
            K = Ko > K ? Ko : K;
            z1 += u[1]; e1 += u[2]; z2 += u[3];
        }
    }
    const float iz = 1.0f / z1;
    const int myidx = 511 - (int)(K & 0x1FFu);

    // ---- phase 5: scale by 1/Z1 (shfl from owner lane) and store ----
#pragma unroll
    for (int rg = 0; rg < 4; rg++) {
#pragma unroll
        for (int reg = 0; reg < 4; reg++) {
            int r = rg * 16 + q4 * 4 + reg;
            float izr = __shfl(iz, r, 64);
            float* orow = outRQ + (size_t)(row0 + r) * C_DIM + (w << 6) + li;
#pragma unroll
            for (int nt = 0; nt < 4; nt++) orow[nt * 16] = acc2[rg * 4 + nt][reg] * izr;
        }
    }

    // ---- phase 6: fused gathering loss: mean((q_norm - values[idx])^2) ----
    float gacc = 0.f;
#pragma unroll
    for (int rr = 0; rr < 8; rr++) {
        int r = (w << 3) + rr;
        int idxr = __shfl(myidx, r, 64);
        const float4* qr = (const float4*)(query + (size_t)(row0 + r) * C_DIM);
        float4 a = qr[l * 2], b = qr[l * 2 + 1];
        float ss = a.x * a.x + a.y * a.y + a.z * a.z + a.w * a.w +
                   b.x * b.x + b.y * b.y + b.z * b.z + b.w * b.w;
        ss = rowAdd16(ss);                           // intra-row16 on VALU
        ss += __shfl_xor(ss, 16, 64);
        ss += __shfl_xor(ss, 32, 64);
        float inv = 1.0f / fmaxf(sqrtf(ss), 1e-12f);
        const float4* vr = (const float4*)(values + (size_t)idxr * C_DIM);
        float4 va = vr[l * 2], vb = vr[l * 2 + 1];
        float d;
        d = a.x * inv - va.x; gacc += d * d;
        d = a.y * inv - va.y; gacc += d * d;
        d = a.z * inv - va.z; gacc += d * d;
        d = a.w * inv - va.w; gacc += d * d;
        d = b.x * inv - vb.x; gacc += d * d;
        d = b.y * inv - vb.y; gacc += d * d;
        d = b.z * inv - vb.z; gacc += d * d;
        d = b.w * inv - vb.w; gacc += d * d;
    }
    gacc = rowAdd16(gacc);
    gacc += __shfl_xor(gacc, 16, 64);
    gacc += __shfl_xor(gacc, 32, 64);
    if (l == 0) gpart[w] = gacc;

    // ---- phase 7: scalars (wave 0 only), off the critical path ----
    if (w == 0) {
        unsigned um = (K >> 31) ? (K & 0x7FFFFFFFu) : ~K;
        um &= ~0x1FFu;
        float m1 = __builtin_bit_cast(float, um);         // ~max s for this row
        float ent = __logf(z1) - e1 * iz;                 // logZ - E[s]
        float con = __logf(z2) - 2.0f * m1;               // -logp[idx] of logits = 2s
#pragma unroll
        for (int msk = 1; msk < 64; msk <<= 1) {
            ent += __shfl_xor(ent, msk, 64);
            con += __shfl_xor(con, msk, 64);
        }
        if (l == 0) {
            atomicAdd(&scal[0], ent * (1.0f / 32768.0f));
            atomicAdd(&scal[2], con * (1.0f / 12800.0f));
        }
    }
    __syncthreads();
    if (tid == 0) {
        float s = 0.f;
#pragma unroll
        for (int i = 0; i < 8; i++) s += gpart[i];
        atomicAdd(&scal[1], s * (1.0f / (32768.0f * 512.0f)));
    }
}

extern "C" void kernel_launch(void* const* d_in, const int* in_sizes, int n_in,
                              void* d_out, int out_size, void* d_ws, size_t ws_size,
                              hipStream_t stream) {
    (void)in_sizes; (void)n_in; (void)out_size; (void)ws_size;
    const float* key    = (const float*)d_in[0];
    const float* query  = (const float*)d_in[1];
    const float* keysIn = (const float*)d_in[2];
    const float* valsIn = (const float*)d_in[3];
    float* out = (float*)d_out;

    unsigned short* keysFrag = (unsigned short*)d_ws;            // 512 KB
    unsigned short* valsFrag = keysFrag + 512 * 512;             // 512 KB

    float* outRQ   = out;                       // 16777216 floats
    float* scal    = out + 16777216;            // entropy, gathering, contrast
    float* keysOut = out + 16777219;            // 262144 floats
    float* valsOut = keysOut + 262144;          // 262144 floats

    pack_kernel<<<384, 256, 0, stream>>>(keysIn, valsIn, keysFrag, valsFrag,
                                         keysOut, valsOut, scal);
    fused_kernel<<<512, 512, 0, stream>>>(key, query, keysFrag, valsFrag, valsIn, outRQ, scal);
}

// Round 6
// 235.674 us; speedup vs baseline: 1.2130x; 1.0177x over previous
//
#include <hip/hip_runtime.h>

typedef short short8 __attribute__((ext_vector_type(8)));
typedef float floatx4 __attribute__((ext_vector_type(4)));

#define C_DIM 512
#define KQ_STRIDE 1040   // bytes per row of the LDS k/p tile (512*2 + 16 pad)
#define ROWS 128         // rows per block (128-row tile: halves B-frag L2 streaming)

__device__ __forceinline__ unsigned short f2bf(float f) {
    unsigned u = __builtin_bit_cast(unsigned, f);
    u = u + 0x7fffu + ((u >> 16) & 1u);
    return (unsigned short)(u >> 16);
}

// Monotone uint key for argmax (max s, then min col); 9 low bits carry 511-col.
__device__ __forceinline__ unsigned skey(float s, int col) {
    unsigned u = __builtin_bit_cast(unsigned, s);
    u = ((int)u < 0) ? ~u : (u | 0x80000000u);
    return (u & ~0x1FFu) | (unsigned)(511 - col);
}

// ---- DPP 16-lane-row reductions on the VALU pipe ----
template <int CTRL>
__device__ __forceinline__ float dppAddF(float x) {
    int t = __builtin_amdgcn_update_dpp(0, __builtin_bit_cast(int, x), CTRL, 0xF, 0xF, true);
    return x + __builtin_bit_cast(float, t);
}
template <int CTRL>
__device__ __forceinline__ unsigned dppMaxU(unsigned x) {
    unsigned u = (unsigned)__builtin_amdgcn_update_dpp(0, (int)x, CTRL, 0xF, 0xF, true);
    return u > x ? u : x;
}
__device__ __forceinline__ float rowAdd16(float x) {
    x = dppAddF<0xB1>(x);
    x = dppAddF<0x4E>(x);
    x = dppAddF<0x124>(x);
    x = dppAddF<0x128>(x);
    return x;
}

// ---------------- pack kernel: keys/values -> B-frag order + passthrough copies + scal zero
__global__ __launch_bounds__(256) void pack_kernel(
    const float* __restrict__ keys, const float* __restrict__ values,
    unsigned short* __restrict__ keysFrag, unsigned short* __restrict__ valsFrag,
    float* __restrict__ keysOut, float* __restrict__ valsOut,
    float* __restrict__ scal) {
    int tid = blockIdx.x * 256 + threadIdx.x;
    if (tid < 65536) {
        int e  = tid & 32767;
        int l  = e & 63;
        int NT = (e >> 6) & 31;
        int kt = e >> 11;                           // 0..15
        int li = l & 15, q4 = l >> 4;
        unsigned short tmp[8];
        if (tid < 32768) {
            // score GEMM: B[k][n] = keys[n][k], keys is [M, C] row-major
            const float* s = keys + (size_t)(NT * 16 + li) * C_DIM + kt * 32 + q4 * 8;
#pragma unroll
            for (int j = 0; j < 8; j++) tmp[j] = f2bf(s[j]);
            unsigned short* d = keysFrag + ((size_t)(kt * 32 + NT) * 64 + l) * 8;
            *(ushort4*)d       = make_ushort4(tmp[0], tmp[1], tmp[2], tmp[3]);
            *(ushort4*)(d + 4) = make_ushort4(tmp[4], tmp[5], tmp[6], tmp[7]);
        } else {
            // PV GEMM: B[k][n] = values[k][n], k indexes M
#pragma unroll
            for (int j = 0; j < 8; j++)
                tmp[j] = f2bf(values[(size_t)(kt * 32 + q4 * 8 + j) * C_DIM + NT * 16 + li]);
            unsigned short* d = valsFrag + ((size_t)(kt * 32 + NT) * 64 + l) * 8;
            *(ushort4*)d       = make_ushort4(tmp[0], tmp[1], tmp[2], tmp[3]);
            *(ushort4*)(d + 4) = make_ushort4(tmp[4], tmp[5], tmp[6], tmp[7]);
        }
    } else {
        int ct = tid - 65536;                       // 0..32767
        if (ct == 0) { scal[0] = 0.f; scal[1] = 0.f; scal[2] = 0.f; }
#pragma unroll
        for (int i = 0; i < 4; i++) {
            int idx = ct + i * 32768;               // 0..131071 float4s
            if (idx < 65536) ((float4*)keysOut)[idx] = ((const float4*)keys)[idx];
            else             ((float4*)valsOut)[idx - 65536] = ((const float4*)values)[idx - 65536];
        }
    }
}

// ---------------- fused main kernel: 128 rows per block, 512 threads (8 waves)
// 128-row tile: each block still reads all 512KB of each frag buffer, but only
// 256 blocks exist -> total B-frag L2 traffic halves vs the 64-row tile, and
// per-CU (1 block/CU) the L2-bound window inside each GEMM phase halves.
// LDS 149.5KB (of 160KB) -> exactly 1 block/CU. Per-kt ILP doubles (32 MFMA)
// to compensate for 2 waves/SIMD.
__global__ __launch_bounds__(512, 2) void fused_kernel(
    const float* __restrict__ key,
    const float* __restrict__ query,
    const unsigned short* __restrict__ keysFrag,
    const unsigned short* __restrict__ valsFrag,
    const float* __restrict__ values,
    float* __restrict__ outRQ,
    float* __restrict__ scal) {   // [0]=entropy, [1]=gather, [2]=contrast
    __shared__ char kq[ROWS * KQ_STRIDE];             // k bf16 tile, later reused as p tile
    __shared__ __align__(16) float stats[8][ROWS][4]; // [wave][row][key,z1,e1,z2]
    __shared__ float gpart[8];

    const int tid = threadIdx.x;
    const int w  = tid >> 6;
    const int l  = tid & 63;
    const int li = l & 15;
    const int q4 = l >> 4;
    const int row0 = blockIdx.x << 7;

    // ---- query L3-warm touch: 1 float per 128B line of this block's query slice ----
    const float* qtb = query + (size_t)row0 * C_DIM;
    float tch0 = qtb[(tid)        * 32];
    float tch1 = qtb[(tid +  512) * 32];
    float tch2 = qtb[(tid + 1024) * 32];
    float tch3 = qtb[(tid + 1536) * 32];

    // ---- phase 0: load 16 rows/wave, l2-normalize, write bf16 to LDS ----
#pragma unroll
    for (int it = 0; it < 4; it++) {
        int r = (w << 4) + (it << 2) + q4;                      // 16 lanes per row
        const float4* src = (const float4*)(key + (size_t)(row0 + r) * C_DIM);
        float4 v[8];
        float ss = 0.f;
#pragma unroll
        for (int i = 0; i < 8; i++) {
            v[i] = src[i * 16 + li];
            ss += v[i].x * v[i].x + v[i].y * v[i].y + v[i].z * v[i].z + v[i].w * v[i].w;
        }
        ss = rowAdd16(ss);
        float inv = 1.0f / fmaxf(sqrtf(ss), 1e-12f);
        char* dstrow = kq + r * KQ_STRIDE;
#pragma unroll
        for (int i = 0; i < 8; i++) {
            ushort4 b = make_ushort4(f2bf(v[i].x * inv), f2bf(v[i].y * inv),
                                     f2bf(v[i].z * inv), f2bf(v[i].w * inv));
            *(ushort4*)(dstrow + i * 128 + li * 8) = b;
        }
    }
    asm volatile("" :: "v"(tch0), "v"(tch1), "v"(tch2), "v"(tch3));
    __syncthreads();

    // ---- phase 1: score GEMM, 128 rows x cols [w*64, +64), B prefetched one kt ahead ----
    floatx4 acc1[32];                        // [rg*4+nt], rg 0..7
#pragma unroll
    for (int i = 0; i < 32; i++) acc1[i] = (floatx4){0.f, 0.f, 0.f, 0.f};
    {
        const short8* kf = (const short8*)keysFrag;
        short8 bcur[4], bnxt[4];
#pragma unroll
        for (int nt = 0; nt < 4; nt++) bcur[nt] = kf[(size_t)((w * 4 + nt) * 64 + l)];
        for (int kt = 0; kt < 16; kt++) {
            if (kt < 15) {
#pragma unroll
                for (int nt = 0; nt < 4; nt++)
                    bnxt[nt] = kf[(size_t)(((kt + 1) * 32 + w * 4 + nt) * 64 + l)];
            }
            short8 a[8];
#pragma unroll
            for (int rg = 0; rg < 8; rg++)
                a[rg] = *(const short8*)(kq + (rg * 16 + li) * KQ_STRIDE + kt * 64 + q4 * 16);
#pragma unroll
            for (int rg = 0; rg < 8; rg++)
#pragma unroll
                for (int nt = 0; nt < 4; nt++)
                    acc1[rg * 4 + nt] = __builtin_amdgcn_mfma_f32_16x16x32_bf16(
                        a[rg], bcur[nt], acc1[rg * 4 + nt], 0, 0, 0);
#pragma unroll
            for (int nt = 0; nt < 4; nt++) bcur[nt] = bnxt[nt];
        }
    }

    // ---- phase 2: per-row partial stats (shiftless, DPP reductions), acc1 -> p ----
#pragma unroll
    for (int rg = 0; rg < 8; rg++) {
#pragma unroll
        for (int reg = 0; reg < 4; reg++) {
            const int colbase = (w << 6) + li;
            float s0 = acc1[rg * 4 + 0][reg];
            float s1 = acc1[rg * 4 + 1][reg];
            float s2 = acc1[rg * 4 + 2][reg];
            float s3 = acc1[rg * 4 + 3][reg];
            unsigned K  = skey(s0, colbase);
            unsigned K1 = skey(s1, colbase + 16);
            unsigned K2 = skey(s2, colbase + 32);
            unsigned K3 = skey(s3, colbase + 48);
            K = K1 > K ? K1 : K;
            K = K2 > K ? K2 : K;
            K = K3 > K ? K3 : K;
            float p0 = __expf(s0), p1 = __expf(s1), p2 = __expf(s2), p3 = __expf(s3);
            float z1 = (p0 + p1) + (p2 + p3);
            float e1 = p0 * s0 + p1 * s1 + p2 * s2 + p3 * s3;
            float z2 = p0 * p0 + p1 * p1 + p2 * p2 + p3 * p3;
            acc1[rg * 4 + 0][reg] = p0;
            acc1[rg * 4 + 1][reg] = p1;
            acc1[rg * 4 + 2][reg] = p2;
            acc1[rg * 4 + 3][reg] = p3;
            K = dppMaxU<0xB1>(K);  z1 = dppAddF<0xB1>(z1);  e1 = dppAddF<0xB1>(e1);  z2 = dppAddF<0xB1>(z2);
            K = dppMaxU<0x4E>(K);  z1 = dppAddF<0x4E>(z1);  e1 = dppAddF<0x4E>(e1);  z2 = dppAddF<0x4E>(z2);
            K = dppMaxU<0x124>(K); z1 = dppAddF<0x124>(z1); e1 = dppAddF<0x124>(e1); z2 = dppAddF<0x124>(z2);
            K = dppMaxU<0x128>(K); z1 = dppAddF<0x128>(z1); e1 = dppAddF<0x128>(e1); z2 = dppAddF<0x128>(z2);
            if (li == 0) {
                floatx4 sv;
                sv[0] = __builtin_bit_cast(float, K);
                sv[1] = z1; sv[2] = e1; sv[3] = z2;
                *(floatx4*)stats[w][rg * 16 + q4 * 4 + reg] = sv;
            }
        }
    }
    __syncthreads();

    // ---- phase 3: p (already in acc1) -> bf16, overwrite kq ----
#pragma unroll
    for (int rg = 0; rg < 8; rg++) {
#pragma unroll
        for (int reg = 0; reg < 4; reg++) {
            int r = rg * 16 + q4 * 4 + reg;
#pragma unroll
            for (int nt = 0; nt < 4; nt++) {
                int col = (w << 6) + nt * 16 + li;
                *(unsigned short*)(kq + r * KQ_STRIDE + col * 2) = f2bf(acc1[rg * 4 + nt][reg]);
            }
        }
    }
    __syncthreads();

    // ---- phase 4: PV GEMM, 128 rows x out cols [w*64, +64) ----
    floatx4 acc2[32];
#pragma unroll
    for (int i = 0; i < 32; i++) acc2[i] = (floatx4){0.f, 0.f, 0.f, 0.f};
    {
        const short8* vf = (const short8*)valsFrag;
        short8 bcur[4], bnxt[4];
#pragma unroll
        for (int nt = 0; nt < 4; nt++) bcur[nt] = vf[(size_t)((w * 4 + nt) * 64 + l)];
        for (int kt = 0; kt < 16; kt++) {
            if (kt < 15) {
#pragma unroll
                for (int nt = 0; nt < 4; nt++)
                    bnxt[nt] = vf[(size_t)(((kt + 1) * 32 + w * 4 + nt) * 64 + l)];
            }
            short8 a[8];
#pragma unroll
            for (int rg = 0; rg < 8; rg++)
                a[rg] = *(const short8*)(kq + (rg * 16 + li) * KQ_STRIDE + kt * 64 + q4 * 16);
#pragma unroll
            for (int rg = 0; rg < 8; rg++)
#pragma unroll
                for (int nt = 0; nt < 4; nt++)
                    acc2[rg * 4 + nt] = __builtin_amdgcn_mfma_f32_16x16x32_bf16(
                        a[rg], bcur[nt], acc2[rg * 4 + nt], 0, 0, 0);
#pragma unroll
            for (int nt = 0; nt < 4; nt++) bcur[nt] = bnxt[nt];
        }
    }

    // ---- phase 4b: cross-wave merge, every wave redundantly; lane l owns rows l and l+64 ----
    unsigned KA, KB; float z1A, e1A, z2A, z1B, e1B, z2B;
    {
        floatx4 vA = *(const floatx4*)stats[0][l];
        floatx4 vB = *(const floatx4*)stats[0][64 + l];
        KA = __builtin_bit_cast(unsigned, vA[0]); z1A = vA[1]; e1A = vA[2]; z2A = vA[3];
        KB = __builtin_bit_cast(unsigned, vB[0]); z1B = vB[1]; e1B = vB[2]; z2B = vB[3];
#pragma unroll
        for (int p = 1; p < 8; p++) {
            floatx4 uA = *(const floatx4*)stats[p][l];
            floatx4 uB = *(const floatx4*)stats[p][64 + l];
            unsigned KoA = __builtin_bit_cast(unsigned, uA[0]);
            unsigned KoB = __builtin_bit_cast(unsigned, uB[0]);
            KA = KoA > KA ? KoA : KA; z1A += uA[1]; e1A += uA[2]; z2A += uA[3];
            KB = KoB > KB ? KoB : KB; z1B += uB[1]; e1B += uB[2]; z2B += uB[3];
        }
    }
    const float izA = 1.0f / z1A;
    const float izB = 1.0f / z1B;
    const int idxA = 511 - (int)(KA & 0x1FFu);
    const int idxB = 511 - (int)(KB & 0x1FFu);

    // ---- phase 5: scale by 1/Z1 (shfl from owner lane) and store ----
#pragma unroll
    for (int rg = 0; rg < 8; rg++) {
#pragma unroll
        for (int reg = 0; reg < 4; reg++) {
            int r = rg * 16 + q4 * 4 + reg;
            float izr = (rg < 4) ? __shfl(izA, r & 63, 64) : __shfl(izB, r & 63, 64);
            float* orow = outRQ + (size_t)(row0 + r) * C_DIM + (w << 6) + li;
#pragma unroll
            for (int nt = 0; nt < 4; nt++) orow[nt * 16] = acc2[rg * 4 + nt][reg] * izr;
        }
    }

    // ---- phase 6: fused gathering loss: mean((q_norm - values[idx])^2) ----
    float gacc = 0.f;
#pragma unroll
    for (int rr = 0; rr < 16; rr++) {
        int r = (w << 4) + rr;
        int idxr = __shfl((w < 4) ? idxA : idxB, r & 63, 64);
        const float4* qr = (const float4*)(query + (size_t)(row0 + r) * C_DIM);
        float4 a = qr[l * 2], b = qr[l * 2 + 1];
        float ss = a.x * a.x + a.y * a.y + a.z * a.z + a.w * a.w +
                   b.x * b.x + b.y * b.y + b.z * b.z + b.w * b.w;
        ss = rowAdd16(ss);
        ss += __shfl_xor(ss, 16, 64);
        ss += __shfl_xor(ss, 32, 64);
        float inv = 1.0f / fmaxf(sqrtf(ss), 1e-12f);
        const float4* vr = (const float4*)(values + (size_t)idxr * C_DIM);
        float4 va = vr[l * 2], vb = vr[l * 2 + 1];
        float d;
        d = a.x * inv - va.x; gacc += d * d;
        d = a.y * inv - va.y; gacc += d * d;
        d = a.z * inv - va.z; gacc += d * d;
        d = a.w * inv - va.w; gacc += d * d;
        d = b.x * inv - vb.x; gacc += d * d;
        d = b.y * inv - vb.y; gacc += d * d;
        d = b.z * inv - vb.z; gacc += d * d;
        d = b.w * inv - vb.w; gacc += d * d;
    }
    gacc = rowAdd16(gacc);
    gacc += __shfl_xor(gacc, 16, 64);
    gacc += __shfl_xor(gacc, 32, 64);
    if (l == 0) gpart[w] = gacc;

    // ---- phase 7: scalars (wave 0 only); lane l carries rows l and l+64 ----
    if (w == 0) {
        unsigned umA = (KA >> 31) ? (KA & 0x7FFFFFFFu) : ~KA;
        unsigned umB = (KB >> 31) ? (KB & 0x7FFFFFFFu) : ~KB;
        umA &= ~0x1FFu; umB &= ~0x1FFu;
        float m1A = __builtin_bit_cast(float, umA);
        float m1B = __builtin_bit_cast(float, umB);
        float ent = (__logf(z1A) - e1A * izA) + (__logf(z1B) - e1B * izB);
        float con = (__logf(z2A) - 2.0f * m1A) + (__logf(z2B) - 2.0f * m1B);
#pragma unroll
        for (int msk = 1; msk < 64; msk <<= 1) {
            ent += __shfl_xor(ent, msk, 64);
            con += __shfl_xor(con, msk, 64);
        }
        if (l == 0) {
            atomicAdd(&scal[0], ent * (1.0f / 32768.0f));
            atomicAdd(&scal[2], con * (1.0f / 12800.0f));
        }
    }
    __syncthreads();
    if (tid == 0) {
        float s = 0.f;
#pragma unroll
        for (int i = 0; i < 8; i++) s += gpart[i];
        atomicAdd(&scal[1], s * (1.0f / (32768.0f * 512.0f)));
    }
}

extern "C" void kernel_launch(void* const* d_in, const int* in_sizes, int n_in,
                              void* d_out, int out_size, void* d_ws, size_t ws_size,
                              hipStream_t stream) {
    (void)in_sizes; (void)n_in; (void)out_size; (void)ws_size;
    const float* key    = (const float*)d_in[0];
    const float* query  = (const float*)d_in[1];
    const float* keysIn = (const float*)d_in[2];
    const float* valsIn = (const float*)d_in[3];
    float* out = (float*)d_out;

    unsigned short* keysFrag = (unsigned short*)d_ws;            // 512 KB
    unsigned short* valsFrag = keysFrag + 512 * 512;             // 512 KB

    float* outRQ   = out;                       // 16777216 floats
    float* scal    = out + 16777216;            // entropy, gathering, contrast
    float* keysOut = out + 16777219;            // 262144 floats
    float* valsOut = keysOut + 262144;          // 262144 floats

    pack_kernel<<<384, 256, 0, stream>>>(keysIn, valsIn, keysFrag, valsFrag,
                                         keysOut, valsOut, scal);
    fused_kernel<<<256, 512, 0, stream>>>(key, query, keysFrag, valsFrag, valsIn, outRQ, scal);
}

// Round 7
// 234.763 us; speedup vs baseline: 1.2177x; 1.0039x over previous
//
#include <hip/hip_runtime.h>

typedef short short8 __attribute__((ext_vector_type(8)));
typedef float floatx4 __attribute__((ext_vector_type(4)));

#define C_DIM 512
#define KQ_STRIDE 1040   // bytes per row of the LDS tile (512*2 + 16 pad)
#define ROWS 128         // rows per block for the two GEMM kernels

__device__ __forceinline__ unsigned short f2bf(float f) {
    unsigned u = __builtin_bit_cast(unsigned, f);
    u = u + 0x7fffu + ((u >> 16) & 1u);
    return (unsigned short)(u >> 16);
}

// Monotone uint key for argmax (max s, then min col); 9 low bits carry 511-col.
__device__ __forceinline__ unsigned skey(float s, int col) {
    unsigned u = __builtin_bit_cast(unsigned, s);
    u = ((int)u < 0) ? ~u : (u | 0x80000000u);
    return (u & ~0x1FFu) | (unsigned)(511 - col);
}

// ---- DPP 16-lane-row reductions on the VALU pipe ----
template <int CTRL>
__device__ __forceinline__ float dppAddF(float x) {
    int t = __builtin_amdgcn_update_dpp(0, __builtin_bit_cast(int, x), CTRL, 0xF, 0xF, true);
    return x + __builtin_bit_cast(float, t);
}
template <int CTRL>
__device__ __forceinline__ unsigned dppMaxU(unsigned x) {
    unsigned u = (unsigned)__builtin_amdgcn_update_dpp(0, (int)x, CTRL, 0xF, 0xF, true);
    return u > x ? u : x;
}
__device__ __forceinline__ float rowAdd16(float x) {
    x = dppAddF<0xB1>(x);
    x = dppAddF<0x4E>(x);
    x = dppAddF<0x124>(x);
    x = dppAddF<0x128>(x);
    return x;
}

// ---------------- pack kernel: keys/values -> B-frag order + passthrough copies + scal zero
__global__ __launch_bounds__(256) void pack_kernel(
    const float* __restrict__ keys, const float* __restrict__ values,
    unsigned short* __restrict__ keysFrag, unsigned short* __restrict__ valsFrag,
    float* __restrict__ keysOut, float* __restrict__ valsOut,
    float* __restrict__ scal) {
    int tid = blockIdx.x * 256 + threadIdx.x;
    if (tid < 65536) {
        int e  = tid & 32767;
        int l  = e & 63;
        int NT = (e >> 6) & 31;
        int kt = e >> 11;                           // 0..15
        int li = l & 15, q4 = l >> 4;
        unsigned short tmp[8];
        if (tid < 32768) {
            // score GEMM: B[k][n] = keys[n][k], keys is [M, C] row-major
            const float* s = keys + (size_t)(NT * 16 + li) * C_DIM + kt * 32 + q4 * 8;
#pragma unroll
            for (int j = 0; j < 8; j++) tmp[j] = f2bf(s[j]);
            unsigned short* d = keysFrag + ((size_t)(kt * 32 + NT) * 64 + l) * 8;
            *(ushort4*)d       = make_ushort4(tmp[0], tmp[1], tmp[2], tmp[3]);
            *(ushort4*)(d + 4) = make_ushort4(tmp[4], tmp[5], tmp[6], tmp[7]);
        } else {
            // PV GEMM: B[k][n] = values[k][n], k indexes M
#pragma unroll
            for (int j = 0; j < 8; j++)
                tmp[j] = f2bf(values[(size_t)(kt * 32 + q4 * 8 + j) * C_DIM + NT * 16 + li]);
            unsigned short* d = valsFrag + ((size_t)(kt * 32 + NT) * 64 + l) * 8;
            *(ushort4*)d       = make_ushort4(tmp[0], tmp[1], tmp[2], tmp[3]);
            *(ushort4*)(d + 4) = make_ushort4(tmp[4], tmp[5], tmp[6], tmp[7]);
        }
    } else {
        int ct = tid - 65536;                       // 0..32767
        if (ct == 0) { scal[0] = 0.f; scal[1] = 0.f; scal[2] = 0.f; }
#pragma unroll
        for (int i = 0; i < 4; i++) {
            int idx = ct + i * 32768;               // 0..131071 float4s
            if (idx < 65536) ((float4*)keysOut)[idx] = ((const float4*)keys)[idx];
            else             ((float4*)valsOut)[idx - 65536] = ((const float4*)values)[idx - 65536];
        }
    }
}

// ---------------- score kernel: norm(key) -> score GEMM -> stats -> p(bf16) + headers
// p[r][c] is stashed in the SECOND half (bytes 1024..2047) of outRQ row r;
// header (bytes 0..7) = { iz=1/Z1 (float), argmax idx (int) }. Within-block RAW
// only (staged through LDS, barriered); across blocks rows are disjoint.
__global__ __launch_bounds__(512, 2) void score_kernel(
    const float* __restrict__ key,
    const unsigned short* __restrict__ keysFrag,
    float* __restrict__ outRQ,
    float* __restrict__ scal) {
    __shared__ char kq[ROWS * KQ_STRIDE];             // k bf16 tile -> p tile
    __shared__ __align__(16) float stats[8][ROWS][4]; // [wave][row][key,z1,e1,z2]

    const int tid = threadIdx.x;
    const int w  = tid >> 6;
    const int l  = tid & 63;
    const int li = l & 15;
    const int q4 = l >> 4;
    const int row0 = blockIdx.x << 7;
    char* outb = (char*)outRQ;

    // ---- phase 0: load 16 rows/wave, l2-normalize, write bf16 to LDS ----
#pragma unroll
    for (int it = 0; it < 4; it++) {
        int r = (w << 4) + (it << 2) + q4;                      // 16 lanes per row
        const float4* src = (const float4*)(key + (size_t)(row0 + r) * C_DIM);
        float4 v[8];
        float ss = 0.f;
#pragma unroll
        for (int i = 0; i < 8; i++) {
            v[i] = src[i * 16 + li];
            ss += v[i].x * v[i].x + v[i].y * v[i].y + v[i].z * v[i].z + v[i].w * v[i].w;
        }
        ss = rowAdd16(ss);
        float inv = 1.0f / fmaxf(sqrtf(ss), 1e-12f);
        char* dstrow = kq + r * KQ_STRIDE;
#pragma unroll
        for (int i = 0; i < 8; i++) {
            ushort4 b = make_ushort4(f2bf(v[i].x * inv), f2bf(v[i].y * inv),
                                     f2bf(v[i].z * inv), f2bf(v[i].w * inv));
            *(ushort4*)(dstrow + i * 128 + li * 8) = b;
        }
    }
    __syncthreads();

    // ---- phase 1: score GEMM, 128 rows x cols [w*64, +64) ----
    floatx4 acc1[32];                        // [rg*4+nt], rg 0..7
#pragma unroll
    for (int i = 0; i < 32; i++) acc1[i] = (floatx4){0.f, 0.f, 0.f, 0.f};
    {
        const short8* kf = (const short8*)keysFrag;
        short8 bcur[4], bnxt[4];
#pragma unroll
        for (int nt = 0; nt < 4; nt++) bcur[nt] = kf[(size_t)((w * 4 + nt) * 64 + l)];
        for (int kt = 0; kt < 16; kt++) {
            if (kt < 15) {
#pragma unroll
                for (int nt = 0; nt < 4; nt++)
                    bnxt[nt] = kf[(size_t)(((kt + 1) * 32 + w * 4 + nt) * 64 + l)];
            }
            short8 a[8];
#pragma unroll
            for (int rg = 0; rg < 8; rg++)
                a[rg] = *(const short8*)(kq + (rg * 16 + li) * KQ_STRIDE + kt * 64 + q4 * 16);
#pragma unroll
            for (int rg = 0; rg < 8; rg++)
#pragma unroll
                for (int nt = 0; nt < 4; nt++)
                    acc1[rg * 4 + nt] = __builtin_amdgcn_mfma_f32_16x16x32_bf16(
                        a[rg], bcur[nt], acc1[rg * 4 + nt], 0, 0, 0);
#pragma unroll
            for (int nt = 0; nt < 4; nt++) bcur[nt] = bnxt[nt];
        }
    }

    // ---- phase 2: per-row partial stats (shiftless, DPP reductions), acc1 -> p ----
#pragma unroll
    for (int rg = 0; rg < 8; rg++) {
#pragma unroll
        for (int reg = 0; reg < 4; reg++) {
            const int colbase = (w << 6) + li;
            float s0 = acc1[rg * 4 + 0][reg];
            float s1 = acc1[rg * 4 + 1][reg];
            float s2 = acc1[rg * 4 + 2][reg];
            float s3 = acc1[rg * 4 + 3][reg];
            unsigned K  = skey(s0, colbase);
            unsigned K1 = skey(s1, colbase + 16);
            unsigned K2 = skey(s2, colbase + 32);
            unsigned K3 = skey(s3, colbase + 48);
            K = K1 > K ? K1 : K;
            K = K2 > K ? K2 : K;
            K = K3 > K ? K3 : K;
            float p0 = __expf(s0), p1 = __expf(s1), p2 = __expf(s2), p3 = __expf(s3);
            float z1 = (p0 + p1) + (p2 + p3);
            float e1 = p0 * s0 + p1 * s1 + p2 * s2 + p3 * s3;
            float z2 = p0 * p0 + p1 * p1 + p2 * p2 + p3 * p3;
            acc1[rg * 4 + 0][reg] = p0;
            acc1[rg * 4 + 1][reg] = p1;
            acc1[rg * 4 + 2][reg] = p2;
            acc1[rg * 4 + 3][reg] = p3;
            K = dppMaxU<0xB1>(K);  z1 = dppAddF<0xB1>(z1);  e1 = dppAddF<0xB1>(e1);  z2 = dppAddF<0xB1>(z2);
            K = dppMaxU<0x4E>(K);  z1 = dppAddF<0x4E>(z1);  e1 = dppAddF<0x4E>(e1);  z2 = dppAddF<0x4E>(z2);
            K = dppMaxU<0x124>(K); z1 = dppAddF<0x124>(z1); e1 = dppAddF<0x124>(e1); z2 = dppAddF<0x124>(z2);
            K = dppMaxU<0x128>(K); z1 = dppAddF<0x128>(z1); e1 = dppAddF<0x128>(e1); z2 = dppAddF<0x128>(z2);
            if (li == 0) {
                floatx4 sv;
                sv[0] = __builtin_bit_cast(float, K);
                sv[1] = z1; sv[2] = e1; sv[3] = z2;
                *(floatx4*)stats[w][rg * 16 + q4 * 4 + reg] = sv;
            }
        }
    }
    __syncthreads();

    // ---- merge + headers + scalars (wave 0 only; lane l owns rows l and l+64) ----
    if (w == 0) {
        unsigned KA, KB; float z1A, e1A, z2A, z1B, e1B, z2B;
        floatx4 vA = *(const floatx4*)stats[0][l];
        floatx4 vB = *(const floatx4*)stats[0][64 + l];
        KA = __builtin_bit_cast(unsigned, vA[0]); z1A = vA[1]; e1A = vA[2]; z2A = vA[3];
        KB = __builtin_bit_cast(unsigned, vB[0]); z1B = vB[1]; e1B = vB[2]; z2B = vB[3];
#pragma unroll
        for (int p = 1; p < 8; p++) {
            floatx4 uA = *(const floatx4*)stats[p][l];
            floatx4 uB = *(const floatx4*)stats[p][64 + l];
            unsigned KoA = __builtin_bit_cast(unsigned, uA[0]);
            unsigned KoB = __builtin_bit_cast(unsigned, uB[0]);
            KA = KoA > KA ? KoA : KA; z1A += uA[1]; e1A += uA[2]; z2A += uA[3];
            KB = KoB > KB ? KoB : KB; z1B += uB[1]; e1B += uB[2]; z2B += uB[3];
        }
        float izA = 1.0f / z1A, izB = 1.0f / z1B;
        int idxA = 511 - (int)(KA & 0x1FFu);
        int idxB = 511 - (int)(KB & 0x1FFu);
        char* h0 = outb + (size_t)(row0 + l) * 2048;
        char* h1 = outb + (size_t)(row0 + 64 + l) * 2048;
        *(float*)h0 = izA; *(int*)(h0 + 4) = idxA;
        *(float*)h1 = izB; *(int*)(h1 + 4) = idxB;
        unsigned umA = (KA >> 31) ? (KA & 0x7FFFFFFFu) : ~KA;
        unsigned umB = (KB >> 31) ? (KB & 0x7FFFFFFFu) : ~KB;
        umA &= ~0x1FFu; umB &= ~0x1FFu;
        float m1A = __builtin_bit_cast(float, umA);
        float m1B = __builtin_bit_cast(float, umB);
        float ent = (__logf(z1A) - e1A * izA) + (__logf(z1B) - e1B * izB);
        float con = (__logf(z2A) - 2.0f * m1A) + (__logf(z2B) - 2.0f * m1B);
#pragma unroll
        for (int msk = 1; msk < 64; msk <<= 1) {
            ent += __shfl_xor(ent, msk, 64);
            con += __shfl_xor(con, msk, 64);
        }
        if (l == 0) {
            atomicAdd(&scal[0], ent * (1.0f / 32768.0f));
            atomicAdd(&scal[2], con * (1.0f / 12800.0f));
        }
    }

    // ---- phase 3: p (in acc1) -> bf16, overwrite kq ----
#pragma unroll
    for (int rg = 0; rg < 8; rg++) {
#pragma unroll
        for (int reg = 0; reg < 4; reg++) {
            int r = rg * 16 + q4 * 4 + reg;
#pragma unroll
            for (int nt = 0; nt < 4; nt++) {
                int col = (w << 6) + nt * 16 + li;
                *(unsigned short*)(kq + r * KQ_STRIDE + col * 2) = f2bf(acc1[rg * 4 + nt][reg]);
            }
        }
    }
    __syncthreads();

    // ---- copy p tile -> global (second half of each outRQ row), coalesced 16B ----
#pragma unroll
    for (int it = 0; it < 16; it++) {
        int r = (w << 4) + it;
        float4 t = *(const float4*)(kq + r * KQ_STRIDE + l * 16);
        *(float4*)(outb + (size_t)(row0 + r) * 2048 + 1024 + l * 16) = t;
    }
}

// ---------------- gather kernel: mean((q_norm - values[idx])^2); idx from row headers.
// MUST run before pv_kernel (which overwrites the headers).
__global__ __launch_bounds__(256) void gather_kernel(
    const float* __restrict__ query,
    const float* __restrict__ values,
    const float* __restrict__ outRQ,
    float* __restrict__ scal) {
    __shared__ float gpart[4];
    const int tid = threadIdx.x;
    const int w = tid >> 6;
    const int l = tid & 63;
    const char* outb = (const char*)outRQ;
    const int row0 = blockIdx.x * 32;

    float gacc = 0.f;
#pragma unroll
    for (int rr = 0; rr < 8; rr++) {
        int r = row0 + w * 8 + rr;
        int idxr = *(const int*)(outb + (size_t)r * 2048 + 4);
        const float4* qr = (const float4*)(query + (size_t)r * C_DIM);
        float4 a = qr[l * 2], b = qr[l * 2 + 1];
        float ss = a.x * a.x + a.y * a.y + a.z * a.z + a.w * a.w +
                   b.x * b.x + b.y * b.y + b.z * b.z + b.w * b.w;
        ss = rowAdd16(ss);
        ss += __shfl_xor(ss, 16, 64);
        ss += __shfl_xor(ss, 32, 64);
        float inv = 1.0f / fmaxf(sqrtf(ss), 1e-12f);
        const float4* vr = (const float4*)(values + (size_t)idxr * C_DIM);
        float4 va = vr[l * 2], vb = vr[l * 2 + 1];
        float d;
        d = a.x * inv - va.x; gacc += d * d;
        d = a.y * inv - va.y; gacc += d * d;
        d = a.z * inv - va.z; gacc += d * d;
        d = a.w * inv - va.w; gacc += d * d;
        d = b.x * inv - vb.x; gacc += d * d;
        d = b.y * inv - vb.y; gacc += d * d;
        d = b.z * inv - vb.z; gacc += d * d;
        d = b.w * inv - vb.w; gacc += d * d;
    }
    gacc = rowAdd16(gacc);
    gacc += __shfl_xor(gacc, 16, 64);
    gacc += __shfl_xor(gacc, 32, 64);
    if (l == 0) gpart[w] = gacc;
    __syncthreads();
    if (tid == 0) {
        float s = gpart[0] + gpart[1] + gpart[2] + gpart[3];
        atomicAdd(&scal[1], s * (1.0f / (32768.0f * 512.0f)));
    }
}

// ---------------- pv kernel: stage p rows -> LDS, PV GEMM, scale by iz, store outRQ
__global__ __launch_bounds__(512, 2) void pv_kernel(
    const unsigned short* __restrict__ valsFrag,
    float* __restrict__ outRQ) {
    __shared__ char kq[ROWS * KQ_STRIDE];
    __shared__ float izsh[ROWS];

    const int tid = threadIdx.x;
    const int w  = tid >> 6;
    const int l  = tid & 63;
    const int li = l & 15;
    const int q4 = l >> 4;
    const int row0 = blockIdx.x << 7;
    char* outb = (char*)outRQ;

    // ---- stage: headers -> izsh, p rows -> LDS tile ----
    if (tid < ROWS) izsh[tid] = *(const float*)(outb + (size_t)(row0 + tid) * 2048);
#pragma unroll
    for (int it = 0; it < 16; it++) {
        int r = (w << 4) + it;
        float4 t = *(const float4*)(outb + (size_t)(row0 + r) * 2048 + 1024 + l * 16);
        *(float4*)(kq + r * KQ_STRIDE + l * 16) = t;
    }
    __syncthreads();

    // ---- PV GEMM, 128 rows x out cols [w*64, +64) ----
    floatx4 acc2[32];
#pragma unroll
    for (int i = 0; i < 32; i++) acc2[i] = (floatx4){0.f, 0.f, 0.f, 0.f};
    {
        const short8* vf = (const short8*)valsFrag;
        short8 bcur[4], bnxt[4];
#pragma unroll
        for (int nt = 0; nt < 4; nt++) bcur[nt] = vf[(size_t)((w * 4 + nt) * 64 + l)];
        for (int kt = 0; kt < 16; kt++) {
            if (kt < 15) {
#pragma unroll
                for (int nt = 0; nt < 4; nt++)
                    bnxt[nt] = vf[(size_t)(((kt + 1) * 32 + w * 4 + nt) * 64 + l)];
            }
            short8 a[8];
#pragma unroll
            for (int rg = 0; rg < 8; rg++)
                a[rg] = *(const short8*)(kq + (rg * 16 + li) * KQ_STRIDE + kt * 64 + q4 * 16);
#pragma unroll
            for (int rg = 0; rg < 8; rg++)
#pragma unroll
                for (int nt = 0; nt < 4; nt++)
                    acc2[rg * 4 + nt] = __builtin_amdgcn_mfma_f32_16x16x32_bf16(
                        a[rg], bcur[nt], acc2[rg * 4 + nt], 0, 0, 0);
#pragma unroll
            for (int nt = 0; nt < 4; nt++) bcur[nt] = bnxt[nt];
        }
    }

    // ---- scale by iz (LDS broadcast) and store; overwrites headers+p with result ----
#pragma unroll
    for (int rg = 0; rg < 8; rg++) {
#pragma unroll
        for (int reg = 0; reg < 4; reg++) {
            int r = rg * 16 + q4 * 4 + reg;
            float izr = izsh[r];
            float* orow = outRQ + (size_t)(row0 + r) * C_DIM + (w << 6) + li;
#pragma unroll
            for (int nt = 0; nt < 4; nt++) orow[nt * 16] = acc2[rg * 4 + nt][reg] * izr;
        }
    }
}

extern "C" void kernel_launch(void* const* d_in, const int* in_sizes, int n_in,
                              void* d_out, int out_size, void* d_ws, size_t ws_size,
                              hipStream_t stream) {
    (void)in_sizes; (void)n_in; (void)out_size; (void)ws_size;
    const float* key    = (const float*)d_in[0];
    const float* query  = (const float*)d_in[1];
    const float* keysIn = (const float*)d_in[2];
    const float* valsIn = (const float*)d_in[3];
    float* out = (float*)d_out;

    unsigned short* keysFrag = (unsigned short*)d_ws;            // 512 KB
    unsigned short* valsFrag = keysFrag + 512 * 512;             // 512 KB

    float* outRQ   = out;                       // 16777216 floats
    float* scal    = out + 16777216;            // entropy, gathering, contrast
    float* keysOut = out + 16777219;            // 262144 floats
    float* valsOut = keysOut + 262144;          // 262144 floats

    pack_kernel<<<384, 256, 0, stream>>>(keysIn, valsIn, keysFrag, valsFrag,
                                         keysOut, valsOut, scal);
    score_kernel<<<256, 512, 0, stream>>>(key, keysFrag, outRQ, scal);
    gather_kernel<<<1024, 256, 0, stream>>>(query, valsIn, outRQ, scal);
    pv_kernel<<<256, 512, 0, stream>>>(valsFrag, outRQ);
}